// Round 3
// baseline (1037.862 us; speedup 1.0000x reference)
//
#include <hip/hip_runtime.h>
#include <math.h>

#define Dd 256
#define Tt 1024
#define Bb 32
#define Kk 1024
#define NROWS (Bb*Tt)            /* 32768 */
#define OUTQ  (Bb*Dd*Tt)         /* 8388608 */

/* workspace layout (bytes) */
#define WS_LOSS 0                /* double            */
#define WS_W2   64               /* float[1024]       */
#define WS_IDX  (WS_W2 + 4*Kk)   /* int[32768]        */

/* ---- w2[k]: numpy-pairwise fp32 sum of w*w per codebook row ---- */
__global__ void vq_w2(const float* __restrict__ cb, float* __restrict__ w2f) {
#pragma clang fp contract(off)
    const int k = blockIdx.x * 256 + threadIdx.x;
    if (k >= Kk) return;
    const float* w = cb + (size_t)k * Dd;
    float h[2];
    for (int half = 0; half < 2; ++half) {
        const float* p = w + half * 128;
        float r[8];
        for (int j = 0; j < 8; ++j) { float v = p[j]; r[j] = v * v; }
        for (int m = 1; m < 16; ++m)
            for (int j = 0; j < 8; ++j) { float v = p[m*8 + j]; r[j] += v * v; }
        h[half] = ((r[0]+r[1]) + (r[2]+r[3])) + ((r[4]+r[5]) + (r[6]+r[7]));
    }
    w2f[k] = h[0] + h[1];
}

/* ---- main: numpy-fp32-exact distance + argmin ----
 * 32 rows/block (xs = 32 KB -> 4 blocks/CU), 256 threads.
 * slab = tid>>5 (0..7): 32-lane half-wave handling codes [slab*128, slab*128+128)
 * for rows = lane&31. Codebook loads are VMEM (no readfirstlane -> vmcnt,
 * decoupled from LDS lgkmcnt -> compiler can pipeline).                    */
__global__ __launch_bounds__(256, 4) void vq_main(const float* __restrict__ latents,
                                                  const float* __restrict__ cb,
                                                  const float* __restrict__ w2f,
                                                  int* __restrict__ idx,
                                                  double* __restrict__ loss_acc) {
    __shared__ float  xs[Dd*32];      /* x tile, [d][row], 32 KB */
    __shared__ float  x2f[32];
    __shared__ float  bsd[8*32];
    __shared__ int    bci[8*32];
    __shared__ double red[32];

    const int tid = threadIdx.x;
    const int rr  = tid & 31;
    const int dg  = tid >> 5;
    const int blk = blockIdx.x;       /* 1024 blocks x 32 rows */
    const int bb  = blk >> 5;
    const int t0  = (blk & 31) << 5;

    const float* lat = latents + (size_t)bb * Dd * Tt + t0;
    for (int d = dg; d < Dd; d += 8)
        xs[d*32 + rr] = lat[(size_t)d * Tt + rr];
    __syncthreads();

    /* x2 per row: exact numpy pairwise (two 128-blocks, 8 accumulators) */
    if (tid < 32) {
#pragma clang fp contract(off)
        float h[2];
        for (int half = 0; half < 2; ++half) {
            float r[8];
            for (int j = 0; j < 8; ++j) {
                float v = xs[(half*128 + j)*32 + tid];
                r[j] = v * v;
            }
            for (int m = 1; m < 16; ++m)
                for (int j = 0; j < 8; ++j) {
                    float v = xs[(half*128 + m*8 + j)*32 + tid];
                    r[j] += v * v;
                }
            h[half] = ((r[0]+r[1]) + (r[2]+r[3])) + ((r[4]+r[5]) + (r[6]+r[7]));
        }
        x2f[tid] = h[0] + h[1];
    }
    __syncthreads();

    const int r    = tid & 31;        /* row within block */
    const int slab = tid >> 5;        /* 0..7 ascending code range (kept in VGPR!) */
    const float x2r = x2f[r];

    float best  = 3.4e38f;
    int   bestc = 0;
    for (int cg = 0; cg < 16; ++cg) {
        const int c0 = slab*128 + cg*8;
        float acc[8];
#pragma unroll
        for (int g = 0; g < 8; ++g) acc[g] = 0.0f;
        /* sequential fp32 FMA chain over k=0..255 per code (BLAS sgemm order) */
        for (int kc = 0; kc < 32; ++kc) {
            float xk[8];
#pragma unroll
            for (int j = 0; j < 8; ++j)
                xk[j] = xs[(kc*8 + j)*32 + r];
#pragma unroll
            for (int g = 0; g < 8; ++g) {
                const float4* wp = (const float4*)(cb + (size_t)(c0 + g)*Dd + kc*8);
                float4 wa = wp[0];
                float4 wb = wp[1];
                acc[g] = __builtin_fmaf(xk[0], wa.x, acc[g]);
                acc[g] = __builtin_fmaf(xk[1], wa.y, acc[g]);
                acc[g] = __builtin_fmaf(xk[2], wa.z, acc[g]);
                acc[g] = __builtin_fmaf(xk[3], wa.w, acc[g]);
                acc[g] = __builtin_fmaf(xk[4], wb.x, acc[g]);
                acc[g] = __builtin_fmaf(xk[5], wb.y, acc[g]);
                acc[g] = __builtin_fmaf(xk[6], wb.z, acc[g]);
                acc[g] = __builtin_fmaf(xk[7], wb.w, acc[g]);
            }
        }
#pragma unroll
        for (int g = 0; g < 8; ++g) {
            /* d = fl(fl(x2 - fl(2*M)) + w2); 2*acc exact -> contraction value-identical */
            float t2 = x2r - 2.0f * acc[g];
            float dv = t2 + w2f[c0 + g];
            if (dv < best) { best = dv; bestc = c0 + g; }   /* first-min, ascending */
        }
    }

    bsd[slab*32 + r] = best;
    bci[slab*32 + r] = bestc;
    __syncthreads();

    if (tid < 32) {
        float b0 = bsd[tid];
        int   ci = bci[tid];
#pragma unroll
        for (int s = 1; s < 8; ++s) {     /* ascending code slabs: strict < == first-min */
            float b1 = bsd[s*32 + tid];
            if (b1 < b0) { b0 = b1; ci = bci[s*32 + tid]; }
        }
        idx[blk*32 + tid] = ci;
        red[tid] = (double)b0;            /* chosen squared distance (fp32 value) */
    }
    __syncthreads();
    if (tid == 0) {
        double s = 0.0;
        for (int i = 0; i < 32; ++i) s += red[i];
        atomicAdd(loss_acc, s);
    }
}

/* ---- gather: out[b][d][t] = cb[idx[b*T+t]][d] ---- */
__global__ void vq_gather(const float* __restrict__ cb,
                          const int* __restrict__ idx,
                          float* __restrict__ out) {
    const size_t g = (size_t)blockIdx.x * 256 + threadIdx.x;
    const int t  = (int)(g & 1023);
    const int d4 = (int)((g >> 10) & 63);
    const int b  = (int)(g >> 16);
    const int i  = idx[b*Tt + t];
    const float4 w4 = *(const float4*)(cb + (size_t)i*Dd + d4*4);
    float* o = out + ((size_t)(b*Dd + d4*4)) * Tt + t;
    o[0]    = w4.x;
    o[Tt]   = w4.y;
    o[2*Tt] = w4.z;
    o[3*Tt] = w4.w;
}

/* ---- finalize: indices as float + loss ---- */
__global__ void vq_finalize(const int* __restrict__ idx,
                            const double* __restrict__ loss_acc,
                            float* __restrict__ out) {
    const int r = blockIdx.x * 256 + threadIdx.x;
    if (r < NROWS) out[OUTQ + 1 + r] = (float)idx[r];
    if (r == 0)    out[OUTQ] = (float)(1.25 * loss_acc[0] / (double)OUTQ);
}

extern "C" void kernel_launch(void* const* d_in, const int* in_sizes, int n_in,
                              void* d_out, int out_size, void* d_ws, size_t ws_size,
                              hipStream_t stream) {
    const float* latents = (const float*)d_in[0];
    const float* cb      = (const float*)d_in[1];
    float* out = (float*)d_out;
    char*  ws  = (char*)d_ws;

    double* loss_acc = (double*)(ws + WS_LOSS);
    float*  w2f      = (float*)(ws + WS_W2);
    int*    idx      = (int*)(ws + WS_IDX);

    hipMemsetAsync(loss_acc, 0, sizeof(double), stream);
    vq_w2<<<(Kk + 255)/256, 256, 0, stream>>>(cb, w2f);
    vq_main<<<NROWS/32, 256, 0, stream>>>(latents, cb, w2f, idx, loss_acc);
    vq_gather<<<(Bb*(Dd/4)*Tt)/256, 256, 0, stream>>>(cb, idx, out);
    vq_finalize<<<(NROWS + 255)/256, 256, 0, stream>>>(idx, loss_acc, out);
}

// Round 4
// 1029.115 us; speedup vs baseline: 1.0085x; 1.0085x over previous
//
#include <hip/hip_runtime.h>
#include <math.h>

#define Dd 256
#define Tt 1024
#define Bb 32
#define Kk 1024
#define NROWS (Bb*Tt)            /* 32768 */
#define OUTQ  (Bb*Dd*Tt)         /* 8388608 */

/* workspace layout (bytes) */
#define WS_LOSS 0                /* double            */
#define WS_W2   64               /* float[1024]       */
#define WS_IDX  (WS_W2 + 4*Kk)   /* int[32768]        */

/* ---- w2[k]: numpy-pairwise fp32 sum of w*w per codebook row ---- */
__global__ void vq_w2(const float* __restrict__ cb, float* __restrict__ w2f) {
#pragma clang fp contract(off)
    const int k = blockIdx.x * 256 + threadIdx.x;
    if (k >= Kk) return;
    const float* w = cb + (size_t)k * Dd;
    float h[2];
    for (int half = 0; half < 2; ++half) {
        const float* p = w + half * 128;
        float r[8];
        for (int j = 0; j < 8; ++j) { float v = p[j]; r[j] = v * v; }
        for (int m = 1; m < 16; ++m)
            for (int j = 0; j < 8; ++j) { float v = p[m*8 + j]; r[j] += v * v; }
        h[half] = ((r[0]+r[1]) + (r[2]+r[3])) + ((r[4]+r[5]) + (r[6]+r[7]));
    }
    w2f[k] = h[0] + h[1];
}

/* ---- main: numpy-fp32-exact distance + argmin ----
 * 32 rows/block (xs = 32 KB -> 4 blocks/CU = 4 waves/SIMD), 256 threads.
 * Half-wave r=tid&31 is the row; slab=tid>>5 picks a 128-code range (VGPR,
 * so codebook loads are VMEM/vmcnt, decoupled from the LDS lgkm queue).
 * Codebook is software-pipelined through two 8xfloat4 VGPR banks so the
 * compiler can wait vmcnt(N>0) instead of draining per 8-FMA step.       */
__global__ __launch_bounds__(256, 4) void vq_main(const float* __restrict__ latents,
                                                  const float* __restrict__ cb,
                                                  const float* __restrict__ w2f,
                                                  int* __restrict__ idx,
                                                  double* __restrict__ loss_acc) {
    __shared__ float  xs[Dd*32];      /* x tile, [k][row], 32 KB */
    __shared__ float  x2f[32];
    __shared__ float  bsd[8*32];
    __shared__ int    bci[8*32];
    __shared__ double red[32];

    const int tid = threadIdx.x;
    const int rr  = tid & 31;
    const int dg  = tid >> 5;
    const int blk = blockIdx.x;       /* 1024 blocks x 32 rows */
    const int bb  = blk >> 5;
    const int t0  = (blk & 31) << 5;

    const float* lat = latents + (size_t)bb * Dd * Tt + t0;
    for (int d = dg; d < Dd; d += 8)
        xs[d*32 + rr] = lat[(size_t)d * Tt + rr];
    __syncthreads();

    /* x2 per row: exact numpy pairwise (two 128-blocks, 8 accumulators) */
    if (tid < 32) {
#pragma clang fp contract(off)
        float h[2];
        for (int half = 0; half < 2; ++half) {
            float r[8];
            for (int j = 0; j < 8; ++j) {
                float v = xs[(half*128 + j)*32 + tid];
                r[j] = v * v;
            }
            for (int m = 1; m < 16; ++m)
                for (int j = 0; j < 8; ++j) {
                    float v = xs[(half*128 + m*8 + j)*32 + tid];
                    r[j] += v * v;
                }
            h[half] = ((r[0]+r[1]) + (r[2]+r[3])) + ((r[4]+r[5]) + (r[6]+r[7]));
        }
        x2f[tid] = h[0] + h[1];
    }
    __syncthreads();

    const int r    = tid & 31;        /* row within block */
    const int slab = tid >> 5;        /* 0..7 ascending code range (VGPR!) */
    const float x2r = x2f[r];
    const float* wbase = cb + (size_t)slab * 128 * Dd;

    float best  = 3.4e38f;
    int   bestc = 0;
    for (int cg = 0; cg < 16; ++cg) {
        const float* wp = wbase + cg * 8 * Dd;   /* 8 codes of this group */
        float4 w0[8], w1[8];
#pragma unroll
        for (int g = 0; g < 8; ++g)              /* prefetch k 0..3 */
            w0[g] = *(const float4*)(wp + g*Dd);
        float acc[8];
#pragma unroll
        for (int g = 0; g < 8; ++g) acc[g] = 0.0f;

        for (int kc = 0; kc < 32; ++kc) {
            float xk[8];
#pragma unroll
            for (int j = 0; j < 8; ++j)
                xk[j] = xs[(kc*8 + j)*32 + r];
#pragma unroll
            for (int g = 0; g < 8; ++g)          /* prefetch k kc*8+4..+8 */
                w1[g] = *(const float4*)(wp + g*Dd + kc*8 + 4);
#pragma unroll
            for (int g = 0; g < 8; ++g) {        /* consume w0: k kc*8..+4 */
                acc[g] = __builtin_fmaf(xk[0], w0[g].x, acc[g]);
                acc[g] = __builtin_fmaf(xk[1], w0[g].y, acc[g]);
                acc[g] = __builtin_fmaf(xk[2], w0[g].z, acc[g]);
                acc[g] = __builtin_fmaf(xk[3], w0[g].w, acc[g]);
            }
            if (kc < 31) {
#pragma unroll
                for (int g = 0; g < 8; ++g)      /* prefetch next kc's k ..+4 */
                    w0[g] = *(const float4*)(wp + g*Dd + (kc+1)*8);
            }
#pragma unroll
            for (int g = 0; g < 8; ++g) {        /* consume w1: k kc*8+4..+8 */
                acc[g] = __builtin_fmaf(xk[4], w1[g].x, acc[g]);
                acc[g] = __builtin_fmaf(xk[5], w1[g].y, acc[g]);
                acc[g] = __builtin_fmaf(xk[6], w1[g].z, acc[g]);
                acc[g] = __builtin_fmaf(xk[7], w1[g].w, acc[g]);
            }
        }
#pragma unroll
        for (int g = 0; g < 8; ++g) {
            /* d = fl(fl(x2 - fl(2*M)) + w2); 2*acc exact -> contraction value-identical */
            float t2 = x2r - 2.0f * acc[g];
            float dv = t2 + w2f[slab*128 + cg*8 + g];
            if (dv < best) { best = dv; bestc = slab*128 + cg*8 + g; }
        }
    }

    bsd[slab*32 + r] = best;
    bci[slab*32 + r] = bestc;
    __syncthreads();

    if (tid < 32) {
        float b0 = bsd[tid];
        int   ci = bci[tid];
#pragma unroll
        for (int s = 1; s < 8; ++s) {     /* ascending code slabs: strict < == first-min */
            float b1 = bsd[s*32 + tid];
            if (b1 < b0) { b0 = b1; ci = bci[s*32 + tid]; }
        }
        idx[blk*32 + tid] = ci;
        red[tid] = (double)b0;            /* chosen squared distance (fp32 value) */
    }
    __syncthreads();
    if (tid == 0) {
        double s = 0.0;
        for (int i = 0; i < 32; ++i) s += red[i];
        atomicAdd(loss_acc, s);
    }
}

/* ---- gather: out[b][d][t] = cb[idx[b*T+t]][d] ---- */
__global__ void vq_gather(const float* __restrict__ cb,
                          const int* __restrict__ idx,
                          float* __restrict__ out) {
    const size_t g = (size_t)blockIdx.x * 256 + threadIdx.x;
    const int t  = (int)(g & 1023);
    const int d4 = (int)((g >> 10) & 63);
    const int b  = (int)(g >> 16);
    const int i  = idx[b*Tt + t];
    const float4 w4 = *(const float4*)(cb + (size_t)i*Dd + d4*4);
    float* o = out + ((size_t)(b*Dd + d4*4)) * Tt + t;
    o[0]    = w4.x;
    o[Tt]   = w4.y;
    o[2*Tt] = w4.z;
    o[3*Tt] = w4.w;
}

/* ---- finalize: indices as float + loss ---- */
__global__ void vq_finalize(const int* __restrict__ idx,
                            const double* __restrict__ loss_acc,
                            float* __restrict__ out) {
    const int r = blockIdx.x * 256 + threadIdx.x;
    if (r < NROWS) out[OUTQ + 1 + r] = (float)idx[r];
    if (r == 0)    out[OUTQ] = (float)(1.25 * loss_acc[0] / (double)OUTQ);
}

extern "C" void kernel_launch(void* const* d_in, const int* in_sizes, int n_in,
                              void* d_out, int out_size, void* d_ws, size_t ws_size,
                              hipStream_t stream) {
    const float* latents = (const float*)d_in[0];
    const float* cb      = (const float*)d_in[1];
    float* out = (float*)d_out;
    char*  ws  = (char*)d_ws;

    double* loss_acc = (double*)(ws + WS_LOSS);
    float*  w2f      = (float*)(ws + WS_W2);
    int*    idx      = (int*)(ws + WS_IDX);

    hipMemsetAsync(loss_acc, 0, sizeof(double), stream);
    vq_w2<<<(Kk + 255)/256, 256, 0, stream>>>(cb, w2f);
    vq_main<<<NROWS/32, 256, 0, stream>>>(latents, cb, w2f, idx, loss_acc);
    vq_gather<<<(Bb*(Dd/4)*Tt)/256, 256, 0, stream>>>(cb, idx, out);
    vq_finalize<<<(NROWS + 255)/256, 256, 0, stream>>>(idx, loss_acc, out);
}

// Round 5
// 746.997 us; speedup vs baseline: 1.3894x; 1.3777x over previous
//
#include <hip/hip_runtime.h>
#include <math.h>

#define Dd 256
#define Tt 1024
#define Bb 32
#define Kk 1024
#define NROWS (Bb*Tt)            /* 32768 */
#define OUTQ  (Bb*Dd*Tt)         /* 8388608 */

typedef float float8_t __attribute__((ext_vector_type(8)));

/* workspace layout (bytes) */
#define WS_LOSS 0                /* double            */
#define WS_W2   64               /* float[1024]       */
#define WS_IDX  (WS_W2 + 4*Kk)   /* int[32768]        */

/* ---- w2[k]: numpy-pairwise fp32 sum of w*w per codebook row ---- */
__global__ void vq_w2(const float* __restrict__ cb, float* __restrict__ w2f) {
#pragma clang fp contract(off)
    const int k = blockIdx.x * 256 + threadIdx.x;
    if (k >= Kk) return;
    const float* w = cb + (size_t)k * Dd;
    float h[2];
    for (int half = 0; half < 2; ++half) {
        const float* p = w + half * 128;
        float r[8];
        for (int j = 0; j < 8; ++j) { float v = p[j]; r[j] = v * v; }
        for (int m = 1; m < 16; ++m)
            for (int j = 0; j < 8; ++j) { float v = p[m*8 + j]; r[j] += v * v; }
        h[half] = ((r[0]+r[1]) + (r[2]+r[3])) + ((r[4]+r[5]) + (r[6]+r[7]));
    }
    w2f[k] = h[0] + h[1];
}

/* ---- main: numpy-fp32-exact distance + argmin ----
 * 512 threads = 8 waves, 64 rows/block (lane=row), wave w = codes
 * [w*128, w*128+128). xs 64 KB -> 2 blocks/CU = 16 waves/CU = 4 waves/SIMD
 * (grid 512 = 2 x 256 CUs, exact fit). Codebook w is wave-uniform
 * (readfirstlane) -> s_load into SGPRs: zero VGPR pressure (no spill risk),
 * zero LDS-pipe load; scalar-L2 latency per 8-code batch (~1 drain / 256
 * FMA-cyc, duty ~35%) is covered by 4 waves/SIMD TLP.                     */
__global__ __launch_bounds__(512) void vq_main(const float* __restrict__ latents,
                                               const float* __restrict__ cb,
                                               const float* __restrict__ w2f,
                                               int* __restrict__ idx,
                                               double* __restrict__ loss_acc) {
    __shared__ float  xs[Dd*64];      /* x tile, [k][row], 64 KB */
    __shared__ float  x2f[64];
    __shared__ float  bsd[8*64];
    __shared__ int    bci[8*64];
    __shared__ double red[64];

    const int tid = threadIdx.x;
    const int rr  = tid & 63;
    const int dg  = tid >> 6;         /* 0..7 */
    const int blk = blockIdx.x;       /* 512 blocks x 64 rows */
    const int bb  = blk >> 4;         /* batch (16 blocks/batch) */
    const int t0  = (blk & 15) << 6;  /* t offset */

    const float* lat = latents + (size_t)bb * Dd * Tt + t0;
    for (int d = dg; d < Dd; d += 8)
        xs[d*64 + rr] = lat[(size_t)d * Tt + rr];
    __syncthreads();

    /* x2 per row: exact numpy pairwise (two 128-blocks, 8 accumulators) */
    if (tid < 64) {
#pragma clang fp contract(off)
        float h[2];
        for (int half = 0; half < 2; ++half) {
            float r[8];
            for (int j = 0; j < 8; ++j) {
                float v = xs[(half*128 + j)*64 + tid];
                r[j] = v * v;
            }
            for (int m = 1; m < 16; ++m)
                for (int j = 0; j < 8; ++j) {
                    float v = xs[(half*128 + m*8 + j)*64 + tid];
                    r[j] += v * v;
                }
            h[half] = ((r[0]+r[1]) + (r[2]+r[3])) + ((r[4]+r[5]) + (r[6]+r[7]));
        }
        x2f[tid] = h[0] + h[1];
    }
    __syncthreads();

    /* wave-uniform slab -> codebook reads become SMEM (s_load) */
    const int slab = __builtin_amdgcn_readfirstlane(tid >> 6);  /* 0..7 */
    const int lane = tid & 63;        /* lane == row */
    const float x2r = x2f[lane];
    const float* wq = cb + (size_t)slab * 128 * Dd;

    float best  = 3.4e38f;
    int   bestc = 0;
    for (int cg = 0; cg < 16; ++cg) {             /* 16 groups x 8 codes */
        const int c0 = cg * 8;
        float acc[8];
#pragma unroll
        for (int g = 0; g < 8; ++g) acc[g] = 0.0f;
        for (int kc = 0; kc < 32; ++kc) {
            /* one 64-SGPR batch: 8 codes x 8 k (s_load_dwordx8 x 8) */
            float8_t w8[8];
#pragma unroll
            for (int g = 0; g < 8; ++g)
                w8[g] = *(const float8_t*)(wq + (size_t)(c0 + g)*Dd + kc*8);
            float xk[8];
#pragma unroll
            for (int j = 0; j < 8; ++j)
                xk[j] = xs[(kc*8 + j)*64 + lane];
#pragma unroll
            for (int g = 0; g < 8; ++g) {
                acc[g] = __builtin_fmaf(xk[0], w8[g][0], acc[g]);
                acc[g] = __builtin_fmaf(xk[1], w8[g][1], acc[g]);
                acc[g] = __builtin_fmaf(xk[2], w8[g][2], acc[g]);
                acc[g] = __builtin_fmaf(xk[3], w8[g][3], acc[g]);
                acc[g] = __builtin_fmaf(xk[4], w8[g][4], acc[g]);
                acc[g] = __builtin_fmaf(xk[5], w8[g][5], acc[g]);
                acc[g] = __builtin_fmaf(xk[6], w8[g][6], acc[g]);
                acc[g] = __builtin_fmaf(xk[7], w8[g][7], acc[g]);
            }
        }
#pragma unroll
        for (int g = 0; g < 8; ++g) {
            /* d = fl(fl(x2 - fl(2*M)) + w2); 2*acc exact -> contraction value-identical */
            float t2 = x2r - 2.0f * acc[g];
            float dv = t2 + w2f[slab*128 + c0 + g];
            if (dv < best) { best = dv; bestc = slab*128 + c0 + g; }  /* first-min */
        }
    }

    bsd[slab*64 + lane] = best;
    bci[slab*64 + lane] = bestc;
    __syncthreads();

    if (tid < 64) {
        float b0 = bsd[tid];
        int   ci = bci[tid];
#pragma unroll
        for (int s = 1; s < 8; ++s) {     /* ascending code slabs: strict < == first-min */
            float b1 = bsd[s*64 + tid];
            if (b1 < b0) { b0 = b1; ci = bci[s*64 + tid]; }
        }
        idx[blk*64 + tid] = ci;
        red[tid] = (double)b0;            /* chosen squared distance (fp32 value) */
    }
    __syncthreads();
    if (tid == 0) {
        double s = 0.0;
        for (int i = 0; i < 64; ++i) s += red[i];
        atomicAdd(loss_acc, s);
    }
}

/* ---- gather: out[b][d][t] = cb[idx[b*T+t]][d] ---- */
__global__ void vq_gather(const float* __restrict__ cb,
                          const int* __restrict__ idx,
                          float* __restrict__ out) {
    const size_t g = (size_t)blockIdx.x * 256 + threadIdx.x;
    const int t  = (int)(g & 1023);
    const int d4 = (int)((g >> 10) & 63);
    const int b  = (int)(g >> 16);
    const int i  = idx[b*Tt + t];
    const float4 w4 = *(const float4*)(cb + (size_t)i*Dd + d4*4);
    float* o = out + ((size_t)(b*Dd + d4*4)) * Tt + t;
    o[0]    = w4.x;
    o[Tt]   = w4.y;
    o[2*Tt] = w4.z;
    o[3*Tt] = w4.w;
}

/* ---- finalize: indices as float + loss ---- */
__global__ void vq_finalize(const int* __restrict__ idx,
                            const double* __restrict__ loss_acc,
                            float* __restrict__ out) {
    const int r = blockIdx.x * 256 + threadIdx.x;
    if (r < NROWS) out[OUTQ + 1 + r] = (float)idx[r];
    if (r == 0)    out[OUTQ] = (float)(1.25 * loss_acc[0] / (double)OUTQ);
}

extern "C" void kernel_launch(void* const* d_in, const int* in_sizes, int n_in,
                              void* d_out, int out_size, void* d_ws, size_t ws_size,
                              hipStream_t stream) {
    const float* latents = (const float*)d_in[0];
    const float* cb      = (const float*)d_in[1];
    float* out = (float*)d_out;
    char*  ws  = (char*)d_ws;

    double* loss_acc = (double*)(ws + WS_LOSS);
    float*  w2f      = (float*)(ws + WS_W2);
    int*    idx      = (int*)(ws + WS_IDX);

    hipMemsetAsync(loss_acc, 0, sizeof(double), stream);
    vq_w2<<<(Kk + 255)/256, 256, 0, stream>>>(cb, w2f);
    vq_main<<<NROWS/64, 512, 0, stream>>>(latents, cb, w2f, idx, loss_acc);
    vq_gather<<<(Bb*(Dd/4)*Tt)/256, 256, 0, stream>>>(cb, idx, out);
    vq_finalize<<<(NROWS + 255)/256, 256, 0, stream>>>(idx, loss_acc, out);
}

// Round 6
// 446.727 us; speedup vs baseline: 2.3233x; 1.6722x over previous
//
#include <hip/hip_runtime.h>
#include <math.h>

#define Dd 256
#define Tt 1024
#define Bb 32
#define Kk 1024
#define NROWS (Bb*Tt)            /* 32768 */
#define OUTQ  (Bb*Dd*Tt)         /* 8388608 */
#define KP   768                 /* packed K: [hi | lo | hi] */
#define SLACK 3e-4f

typedef __bf16 b16x8 __attribute__((ext_vector_type(8)));
typedef float  f32x4 __attribute__((ext_vector_type(4)));

/* workspace layout (bytes) */
#define OFF_LOSS  0                      /* double              */
#define OFF_W2    256                    /* float[1024]         */
#define OFF_IDX   8192                   /* int[32768]          */
#define OFF_X2    139264                 /* float[32768]        */
#define OFF_CANDC 270336                 /* int[32768]          */
#define OFF_CAND  401408                 /* u16[32768*16] 1MB   */
#define OFF_BT    1449984                /* bf16[1024*768] 1.5M */
#define OFF_X     3022848                /* float[32768*256] 32M*/
#define OFF_DYN   36577280               /* A chunk + G chunk   */
#define MIN_WS    (OFF_DYN + 128*(1536+4096))

/* ---- w2[k]: numpy-pairwise fp32 sum of w*w per codebook row ---- */
__global__ void vq_w2(const float* __restrict__ cb, float* __restrict__ w2f) {
#pragma clang fp contract(off)
    const int k = blockIdx.x * 256 + threadIdx.x;
    if (k >= Kk) return;
    const float* w = cb + (size_t)k * Dd;
    float h[2];
    for (int half = 0; half < 2; ++half) {
        const float* p = w + half * 128;
        float r[8];
        for (int j = 0; j < 8; ++j) { float v = p[j]; r[j] = v * v; }
        for (int m = 1; m < 16; ++m)
            for (int j = 0; j < 8; ++j) { float v = p[m*8 + j]; r[j] += v * v; }
        h[half] = ((r[0]+r[1]) + (r[2]+r[3])) + ((r[4]+r[5]) + (r[6]+r[7]));
    }
    w2f[k] = h[0] + h[1];
}

/* ---- BT[c][k]: packed [w_hi | w_hi | w_lo], bf16 ---- */
__global__ void vq_prep_bt(const float* __restrict__ cb, __bf16* __restrict__ BT) {
    const int c = blockIdx.x, t = threadIdx.x;          /* 1024 x 256 */
    float v = cb[(size_t)c*Dd + t];
    __bf16 hi = (__bf16)v;
    __bf16 lo = (__bf16)(v - (float)hi);
    BT[(size_t)c*KP + t]        = hi;
    BT[(size_t)c*KP + 256 + t]  = hi;
    BT[(size_t)c*KP + 512 + t]  = lo;
}

/* ---- transpose latents -> X[r][d] fp32 (full) + A[r][k] packed bf16 (chunk) */
__global__ void vq_prep_x(const float* __restrict__ lat, float* __restrict__ X,
                          __bf16* __restrict__ A, int r0) {
    __shared__ float tl[64][65];
    const int tid = threadIdx.x;
    const int rowbase = r0 + blockIdx.x * 64;           /* global row, mult of 64 */
    const int b = rowbase >> 10, t0 = rowbase & 1023;
    const int d0 = blockIdx.y * 64;
    const int tt = tid & 63, sub = tid >> 6;
#pragma unroll
    for (int it = 0; it < 16; ++it) {
        int d = it*4 + sub;
        tl[d][tt] = lat[((size_t)(b*Dd + d0 + d))*Tt + t0 + tt];
    }
    __syncthreads();
    const int dd = tid & 63;
#pragma unroll
    for (int it = 0; it < 16; ++it) {
        int t = it*4 + sub;
        float v = tl[dd][t];
        int grow = rowbase + t;
        X[(size_t)grow*Dd + d0 + dd] = v;
        __bf16 hi = (__bf16)v;
        __bf16 lo = (__bf16)(v - (float)hi);
        size_t ab = (size_t)(grow - r0)*KP + d0 + dd;
        A[ab]       = hi;
        A[ab + 256] = lo;
        A[ab + 512] = hi;
    }
}

/* ---- filter GEMM: G[r][n] = w2f[n] - 2 * (A row . BT row), MFMA bf16 ----
 * 128x128 C-tile, 4 waves in 2x2, each wave 4x4 frags of 16x16x32.
 * Verified layouts (m89/m91/m120): A-frag A[m=lane&15][k=quad*8+j],
 * B-frag B[k=quad*8+j][n=lane&15], C/D col=lane&15, row=quad*4+reg.      */
__global__ __launch_bounds__(256) void vq_gemm(const __bf16* __restrict__ A,
                                               const __bf16* __restrict__ BT,
                                               const float* __restrict__ w2f,
                                               float* __restrict__ G) {
    __shared__ __bf16 As[128][72];      /* +8 pad: 2-way-max bank aliasing */
    __shared__ __bf16 Bs[128][72];
    const int tid = threadIdx.x;
    const int bm = blockIdx.x, bn = blockIdx.y;
    const int l = tid & 63, wv = tid >> 6;
    const int wm = (wv & 1) * 64, wn = (wv >> 1) * 64;
    const int m16 = l & 15, quad = l >> 4;

    f32x4 acc[4][4];
#pragma unroll
    for (int i = 0; i < 4; ++i)
#pragma unroll
        for (int j = 0; j < 4; ++j) acc[i][j] = (f32x4){0.f,0.f,0.f,0.f};

    const int sr = tid >> 3;            /* 0..31 */
    const int sk = (tid & 7) * 8;       /* 0..56 */

    for (int kt = 0; kt < 12; ++kt) {
        const int k0 = kt * 64;
#pragma unroll
        for (int p = 0; p < 4; ++p) {
            int r = sr + p*32;
            *(uint4*)&As[r][sk] = *(const uint4*)&A [(size_t)(bm*128 + r)*KP + k0 + sk];
            *(uint4*)&Bs[r][sk] = *(const uint4*)&BT[(size_t)(bn*128 + r)*KP + k0 + sk];
        }
        __syncthreads();
#pragma unroll
        for (int ks = 0; ks < 64; ks += 32) {
            b16x8 a[4], b[4];
#pragma unroll
            for (int i = 0; i < 4; ++i) a[i] = *(const b16x8*)&As[wm + 16*i + m16][ks + quad*8];
#pragma unroll
            for (int j = 0; j < 4; ++j) b[j] = *(const b16x8*)&Bs[wn + 16*j + m16][ks + quad*8];
#pragma unroll
            for (int i = 0; i < 4; ++i)
#pragma unroll
                for (int j = 0; j < 4; ++j)
                    acc[i][j] = __builtin_amdgcn_mfma_f32_16x16x32_bf16(a[i], b[j], acc[i][j], 0, 0, 0);
        }
        __syncthreads();
    }
#pragma unroll
    for (int i = 0; i < 4; ++i)
#pragma unroll
        for (int j = 0; j < 4; ++j) {
            int n = bn*128 + wn + 16*j + m16;
            float w2n = w2f[n];
#pragma unroll
            for (int g = 0; g < 4; ++g) {
                int r = bm*128 + wm + 16*i + quad*4 + g;
                G[(size_t)r*Kk + n] = w2n - 2.0f * acc[i][j][g];
            }
        }
}

/* ---- per-row: filter-min, candidate collect, exact pairwise x2 ---- */
__global__ void vq_collect(const float* __restrict__ G, const float* __restrict__ X,
                           int r0, float* __restrict__ x2v, int* __restrict__ candc,
                           unsigned short* __restrict__ cand) {
    const int grow = blockIdx.x * 256 + threadIdx.x;    /* local row */
    const int row  = r0 + grow;
    const float4* g4 = (const float4*)(G + (size_t)grow * Kk);
    float m1 = 3.4e38f;
    for (int i = 0; i < 256; ++i) {
        float4 v = g4[i];
        m1 = fminf(m1, fminf(fminf(v.x, v.y), fminf(v.z, v.w)));
    }
    const float thr = m1 + SLACK;
    int cnt = 0;
    for (int i = 0; i < 256; ++i) {
        float4 v = g4[i];
        if (v.x <= thr) { if (cnt < 16) cand[(size_t)row*16 + cnt] = (unsigned short)(4*i+0); ++cnt; }
        if (v.y <= thr) { if (cnt < 16) cand[(size_t)row*16 + cnt] = (unsigned short)(4*i+1); ++cnt; }
        if (v.z <= thr) { if (cnt < 16) cand[(size_t)row*16 + cnt] = (unsigned short)(4*i+2); ++cnt; }
        if (v.w <= thr) { if (cnt < 16) cand[(size_t)row*16 + cnt] = (unsigned short)(4*i+3); ++cnt; }
    }
    candc[row] = cnt;
    {
#pragma clang fp contract(off)
        const float* xr = X + (size_t)row * Dd;
        float h[2];
        for (int half = 0; half < 2; ++half) {
            const float* p = xr + half*128;
            float r8[8];
            for (int j = 0; j < 8; ++j) { float v = p[j]; r8[j] = v * v; }
            for (int m = 1; m < 16; ++m)
                for (int j = 0; j < 8; ++j) { float v = p[m*8 + j]; r8[j] += v * v; }
            h[half] = ((r8[0]+r8[1]) + (r8[2]+r8[3])) + ((r8[4]+r8[5]) + (r8[6]+r8[7]));
        }
        x2v[row] = h[0] + h[1];
    }
}

/* ---- rescore candidates with the bit-exact numpy fp32 pipeline ---- */
__global__ __launch_bounds__(256) void vq_rescore(const float* __restrict__ X,
                                                  const float* __restrict__ cb,
                                                  const float* __restrict__ w2f,
                                                  const float* __restrict__ x2v,
                                                  const int* __restrict__ candc,
                                                  const unsigned short* __restrict__ cand,
                                                  int* __restrict__ idx,
                                                  double* __restrict__ loss_acc) {
    __shared__ double part[4];
    const int tid = threadIdx.x;
    const int wv = tid >> 6, l = tid & 63;
    const int row = blockIdx.x * 4 + wv;                /* wave per row */
    int Kc = candc[row]; if (Kc > 16) Kc = 16;
    float dv = 3.4e38f; int c = 1 << 20;
    if (l < Kc) {
        c = cand[(size_t)row*16 + l];
        const float4* xq = (const float4*)(X  + (size_t)row*Dd);
        const float4* wq = (const float4*)(cb + (size_t)c*Dd);
        float acc = 0.0f;
        for (int m = 0; m < 64; ++m) {                  /* strict k-ascending fp32 chain */
            float4 xa = xq[m], wa = wq[m];
            acc = __builtin_fmaf(xa.x, wa.x, acc);
            acc = __builtin_fmaf(xa.y, wa.y, acc);
            acc = __builtin_fmaf(xa.z, wa.z, acc);
            acc = __builtin_fmaf(xa.w, wa.w, acc);
        }
        float t2 = x2v[row] - 2.0f * acc;               /* fl(x2 - fl(2M)) */
        dv = t2 + w2f[c];                               /* fl(.. + w2)     */
    }
    for (int off = 8; off; off >>= 1) {                 /* lexicographic (dv, c) min */
        float d2 = __shfl_xor(dv, off, 16);
        int   c2 = __shfl_xor(c,  off, 16);
        if (d2 < dv || (d2 == dv && c2 < c)) { dv = d2; c = c2; }
    }
    if (l == 0) { idx[row] = c; part[wv] = (double)dv; }
    __syncthreads();
    if (tid == 0) atomicAdd(loss_acc, part[0] + part[1] + part[2] + part[3]);
}

/* ---- R5 fallback main (s_load path), used only if ws too small ---- */
typedef float float8_t __attribute__((ext_vector_type(8)));
__global__ __launch_bounds__(512) void vq_main(const float* __restrict__ latents,
                                               const float* __restrict__ cb,
                                               const float* __restrict__ w2f,
                                               int* __restrict__ idx,
                                               double* __restrict__ loss_acc) {
    __shared__ float  xs[Dd*64];
    __shared__ float  x2f[64];
    __shared__ float  bsd[8*64];
    __shared__ int    bci[8*64];
    __shared__ double red[64];
    const int tid = threadIdx.x;
    const int rr  = tid & 63;
    const int dg  = tid >> 6;
    const int blk = blockIdx.x;
    const int bb  = blk >> 4;
    const int t0  = (blk & 15) << 6;
    const float* lat = latents + (size_t)bb * Dd * Tt + t0;
    for (int d = dg; d < Dd; d += 8) xs[d*64 + rr] = lat[(size_t)d * Tt + rr];
    __syncthreads();
    if (tid < 64) {
#pragma clang fp contract(off)
        float h[2];
        for (int half = 0; half < 2; ++half) {
            float r[8];
            for (int j = 0; j < 8; ++j) { float v = xs[(half*128 + j)*64 + tid]; r[j] = v*v; }
            for (int m = 1; m < 16; ++m)
                for (int j = 0; j < 8; ++j) { float v = xs[(half*128 + m*8 + j)*64 + tid]; r[j] += v*v; }
            h[half] = ((r[0]+r[1]) + (r[2]+r[3])) + ((r[4]+r[5]) + (r[6]+r[7]));
        }
        x2f[tid] = h[0] + h[1];
    }
    __syncthreads();
    const int slab = __builtin_amdgcn_readfirstlane(tid >> 6);
    const int lane = tid & 63;
    const float x2r = x2f[lane];
    const float* wq = cb + (size_t)slab * 128 * Dd;
    float best = 3.4e38f; int bestc = 0;
    for (int cg = 0; cg < 16; ++cg) {
        const int c0 = cg * 8;
        float acc[8];
#pragma unroll
        for (int g = 0; g < 8; ++g) acc[g] = 0.0f;
        for (int kc = 0; kc < 32; ++kc) {
            float8_t w8[8];
#pragma unroll
            for (int g = 0; g < 8; ++g) w8[g] = *(const float8_t*)(wq + (size_t)(c0+g)*Dd + kc*8);
            float xk[8];
#pragma unroll
            for (int j = 0; j < 8; ++j) xk[j] = xs[(kc*8 + j)*64 + lane];
#pragma unroll
            for (int g = 0; g < 8; ++g)
#pragma unroll
                for (int j = 0; j < 8; ++j) acc[g] = __builtin_fmaf(xk[j], w8[g][j], acc[g]);
        }
#pragma unroll
        for (int g = 0; g < 8; ++g) {
            float t2 = x2r - 2.0f * acc[g];
            float dvv = t2 + w2f[slab*128 + c0 + g];
            if (dvv < best) { best = dvv; bestc = slab*128 + c0 + g; }
        }
    }
    bsd[slab*64 + lane] = best; bci[slab*64 + lane] = bestc;
    __syncthreads();
    if (tid < 64) {
        float b0 = bsd[tid]; int ci = bci[tid];
#pragma unroll
        for (int s = 1; s < 8; ++s) { float b1 = bsd[s*64 + tid]; if (b1 < b0) { b0 = b1; ci = bci[s*64 + tid]; } }
        idx[blk*64 + tid] = ci; red[tid] = (double)b0;
    }
    __syncthreads();
    if (tid == 0) { double s = 0.0; for (int i = 0; i < 64; ++i) s += red[i]; atomicAdd(loss_acc, s); }
}

/* ---- gather: out[b][d][t] = cb[idx[b*T+t]][d] ---- */
__global__ void vq_gather(const float* __restrict__ cb,
                          const int* __restrict__ idx,
                          float* __restrict__ out) {
    const size_t g = (size_t)blockIdx.x * 256 + threadIdx.x;
    const int t  = (int)(g & 1023);
    const int d4 = (int)((g >> 10) & 63);
    const int b  = (int)(g >> 16);
    const int i  = idx[b*Tt + t];
    const float4 w4 = *(const float4*)(cb + (size_t)i*Dd + d4*4);
    float* o = out + ((size_t)(b*Dd + d4*4)) * Tt + t;
    o[0]    = w4.x;
    o[Tt]   = w4.y;
    o[2*Tt] = w4.z;
    o[3*Tt] = w4.w;
}

/* ---- finalize: indices as float + loss ---- */
__global__ void vq_finalize(const int* __restrict__ idx,
                            const double* __restrict__ loss_acc,
                            float* __restrict__ out) {
    const int r = blockIdx.x * 256 + threadIdx.x;
    if (r < NROWS) out[OUTQ + 1 + r] = (float)idx[r];
    if (r == 0)    out[OUTQ] = (float)(1.25 * loss_acc[0] / (double)OUTQ);
}

extern "C" void kernel_launch(void* const* d_in, const int* in_sizes, int n_in,
                              void* d_out, int out_size, void* d_ws, size_t ws_size,
                              hipStream_t stream) {
    const float* latents = (const float*)d_in[0];
    const float* cb      = (const float*)d_in[1];
    float* out = (float*)d_out;
    char*  ws  = (char*)d_ws;

    double* loss = (double*)(ws + OFF_LOSS);
    float*  w2f  = (float*)(ws + OFF_W2);
    int*    idx  = (int*)(ws + OFF_IDX);

    hipMemsetAsync(loss, 0, sizeof(double), stream);
    vq_w2<<<4, 256, 0, stream>>>(cb, w2f);

    if (ws_size >= (size_t)MIN_WS) {
        float*          x2v   = (float*)(ws + OFF_X2);
        int*            candc = (int*)(ws + OFF_CANDC);
        unsigned short* cand  = (unsigned short*)(ws + OFF_CAND);
        __bf16*         BT    = (__bf16*)(ws + OFF_BT);
        float*          X     = (float*)(ws + OFF_X);

        size_t avail = ws_size - OFF_DYN;
        long long rc = (long long)(avail / (1536 + 4096));
        if (rc > NROWS) rc = NROWS;
        rc &= ~127LL;                                    /* multiple of 128 */
        __bf16* A = (__bf16*)(ws + OFF_DYN);
        float*  G = (float*)(ws + OFF_DYN + (size_t)rc * 1536);

        vq_prep_bt<<<Kk, 256, 0, stream>>>(cb, BT);
        for (int r0 = 0; r0 < NROWS; r0 += (int)rc) {
            int MR = NROWS - r0; if (MR > rc) MR = (int)rc;
            vq_prep_x<<<dim3(MR/64, 4), 256, 0, stream>>>(latents, X, A, r0);
            vq_gemm<<<dim3(MR/128, 8), 256, 0, stream>>>(A, BT, w2f, G);
            vq_collect<<<MR/256, 256, 0, stream>>>(G, X, r0, x2v, candc, cand);
        }
        vq_rescore<<<NROWS/4, 256, 0, stream>>>(X, cb, w2f, x2v, candc, cand, idx, loss);
    } else {
        vq_main<<<NROWS/64, 512, 0, stream>>>(latents, cb, w2f, idx, loss);
    }

    vq_gather<<<(Bb*(Dd/4)*Tt)/256, 256, 0, stream>>>(cb, idx, out);
    vq_finalize<<<(NROWS + 255)/256, 256, 0, stream>>>(idx, loss, out);
}

// Round 7
// 325.437 us; speedup vs baseline: 3.1891x; 1.3727x over previous
//
#include <hip/hip_runtime.h>
#include <math.h>

#define Dd 256
#define Tt 1024
#define Bb 32
#define Kk 1024
#define NROWS (Bb*Tt)            /* 32768 */
#define OUTQ  (Bb*Dd*Tt)         /* 8388608 */
#define KP   768                 /* packed K: [hi | lo | hi] */
#define SLACK 3e-4f

typedef __bf16 b16x8 __attribute__((ext_vector_type(8)));
typedef float  f32x4 __attribute__((ext_vector_type(4)));

/* workspace layout (bytes) */
#define OFF_LOSS  0                      /* double                 */
#define OFF_W2    256                    /* float[1024]            */
#define OFF_IDX   8192                   /* int[32768]             */
#define OFF_CCNT  139264                 /* u32[32768*8]   1 MB    */
#define OFF_CCODE 1187840                /* u16[32768*8*8] 4 MB    */
#define OFF_BT    5382144                /* bf16[1024*768] 1.5 MB  */
#define OFF_DYN   6955008                /* A chunk (1536 B/row)   */
#define MIN_WS    (OFF_DYN + 128*1536)

/* ---- w2[k]: numpy-pairwise fp32 sum of w*w per codebook row ---- */
__global__ void vq_w2(const float* __restrict__ cb, float* __restrict__ w2f) {
#pragma clang fp contract(off)
    const int k = blockIdx.x * 256 + threadIdx.x;
    if (k >= Kk) return;
    const float* w = cb + (size_t)k * Dd;
    float h[2];
    for (int half = 0; half < 2; ++half) {
        const float* p = w + half * 128;
        float r[8];
        for (int j = 0; j < 8; ++j) { float v = p[j]; r[j] = v * v; }
        for (int m = 1; m < 16; ++m)
            for (int j = 0; j < 8; ++j) { float v = p[m*8 + j]; r[j] += v * v; }
        h[half] = ((r[0]+r[1]) + (r[2]+r[3])) + ((r[4]+r[5]) + (r[6]+r[7]));
    }
    w2f[k] = h[0] + h[1];
}

/* ---- BT[c][k]: packed [w_hi | w_hi | w_lo], bf16 ---- */
__global__ void vq_prep_bt(const float* __restrict__ cb, __bf16* __restrict__ BT) {
    const int c = blockIdx.x, t = threadIdx.x;          /* 1024 x 256 */
    float v = cb[(size_t)c*Dd + t];
    __bf16 hi = (__bf16)v;
    __bf16 lo = (__bf16)(v - (float)hi);
    BT[(size_t)c*KP + t]        = hi;
    BT[(size_t)c*KP + 256 + t]  = hi;
    BT[(size_t)c*KP + 512 + t]  = lo;
}

/* ---- transpose latents -> A[r][k] packed [x_hi | x_lo | x_hi] bf16 ---- */
__global__ void vq_prep_a(const float* __restrict__ lat, __bf16* __restrict__ A,
                          int r0) {
    __shared__ float tl[64][65];
    const int tid = threadIdx.x;
    const int rowbase = r0 + blockIdx.x * 64;           /* global row, mult of 64 */
    const int b = rowbase >> 10, t0 = rowbase & 1023;
    const int d0 = blockIdx.y * 64;
    const int tt = tid & 63, sub = tid >> 6;
#pragma unroll
    for (int it = 0; it < 16; ++it) {
        int d = it*4 + sub;
        tl[d][tt] = lat[((size_t)(b*Dd + d0 + d))*Tt + t0 + tt];
    }
    __syncthreads();
    const int dd = tid & 63;
#pragma unroll
    for (int it = 0; it < 16; ++it) {
        int t = it*4 + sub;
        float v = tl[dd][t];
        int grow = rowbase + t;
        __bf16 hi = (__bf16)v;
        __bf16 lo = (__bf16)(v - (float)hi);
        size_t ab = (size_t)(grow - r0)*KP + d0 + dd;
        A[ab]       = hi;
        A[ab + 256] = lo;
        A[ab + 512] = hi;
    }
}

/* ---- filter GEMM + fused min/candidate epilogue ----
 * 128x128 C-tile (bm=row-block, bn=code-slab), 4 waves 2x2, 4x4 frags of
 * 16x16x32 bf16 MFMA. f = w2 - 2S. Epilogue: per-row min over the slab's
 * 128 cols (j-frags + m16 shuffles + LDS cross-wave), then list codes with
 * f <= slabmin + SLACK (cap 8). Writes only ccnt/ccode -- no G.          */
__global__ __launch_bounds__(256) void vq_gemm(const __bf16* __restrict__ A,
                                               const __bf16* __restrict__ BT,
                                               const float* __restrict__ w2f,
                                               unsigned* __restrict__ ccnt,
                                               unsigned short* __restrict__ ccode,
                                               int r0) {
    __shared__ __bf16 As[128][72];
    __shared__ __bf16 Bs[128][72];
    __shared__ float  rminS[128][2];
    __shared__ unsigned cntL[128];
    __shared__ unsigned short codesL[128][8];

    const int tid = threadIdx.x;
    const int bm = blockIdx.x, bn = blockIdx.y;
    const int l = tid & 63, wv = tid >> 6;
    const int wm = (wv & 1) * 64, wn = (wv >> 1) * 64;
    const int m16 = l & 15, quad = l >> 4;

    if (tid < 128) cntL[tid] = 0u;

    f32x4 acc[4][4];
#pragma unroll
    for (int i = 0; i < 4; ++i)
#pragma unroll
        for (int j = 0; j < 4; ++j) acc[i][j] = (f32x4){0.f,0.f,0.f,0.f};

    const int sr = tid >> 3;            /* 0..31 */
    const int sk = (tid & 7) * 8;       /* 0..56 */

    for (int kt = 0; kt < 12; ++kt) {
        const int k0 = kt * 64;
#pragma unroll
        for (int p = 0; p < 4; ++p) {
            int r = sr + p*32;
            *(uint4*)&As[r][sk] = *(const uint4*)&A [(size_t)(bm*128 + r)*KP + k0 + sk];
            *(uint4*)&Bs[r][sk] = *(const uint4*)&BT[(size_t)(bn*128 + r)*KP + k0 + sk];
        }
        __syncthreads();
#pragma unroll
        for (int ks = 0; ks < 64; ks += 32) {
            b16x8 a[4], b[4];
#pragma unroll
            for (int i = 0; i < 4; ++i) a[i] = *(const b16x8*)&As[wm + 16*i + m16][ks + quad*8];
#pragma unroll
            for (int j = 0; j < 4; ++j) b[j] = *(const b16x8*)&Bs[wn + 16*j + m16][ks + quad*8];
#pragma unroll
            for (int i = 0; i < 4; ++i)
#pragma unroll
                for (int j = 0; j < 4; ++j)
                    acc[i][j] = __builtin_amdgcn_mfma_f32_16x16x32_bf16(a[i], b[j], acc[i][j], 0, 0, 0);
        }
        __syncthreads();
    }

    /* ---- epilogue: per-row slab-min + candidates ---- */
    float w2n[4];
#pragma unroll
    for (int j = 0; j < 4; ++j) w2n[j] = w2f[bn*128 + wn + 16*j + m16];

    float vmin[4][4];
#pragma unroll
    for (int i = 0; i < 4; ++i)
#pragma unroll
        for (int g = 0; g < 4; ++g) {
            float v = w2n[0] - 2.0f * acc[i][0][g];
#pragma unroll
            for (int j = 1; j < 4; ++j)
                v = fminf(v, w2n[j] - 2.0f * acc[i][j][g]);
#pragma unroll
            for (int off = 1; off <= 8; off <<= 1)
                v = fminf(v, __shfl_xor(v, off, 64));   /* min over m16 group */
            vmin[i][g] = v;
        }
    if (m16 == 0) {
#pragma unroll
        for (int i = 0; i < 4; ++i)
#pragma unroll
            for (int g = 0; g < 4; ++g)
                rminS[wm + 16*i + quad*4 + g][wn >> 6] = vmin[i][g];
    }
    __syncthreads();
#pragma unroll
    for (int i = 0; i < 4; ++i)
#pragma unroll
        for (int g = 0; g < 4; ++g) {
            const int rloc = wm + 16*i + quad*4 + g;
            const float thr = fminf(rminS[rloc][0], rminS[rloc][1]) + SLACK;
#pragma unroll
            for (int j = 0; j < 4; ++j) {
                float f = w2n[j] - 2.0f * acc[i][j][g];
                if (f <= thr) {
                    unsigned slot = atomicAdd(&cntL[rloc], 1u);
                    if (slot < 8u)
                        codesL[rloc][slot] = (unsigned short)(bn*128 + wn + 16*j + m16);
                }
            }
        }
    __syncthreads();
    if (tid < 128) {
        const int R = r0 + bm*128 + tid;
        unsigned c8 = cntL[tid]; if (c8 > 8u) c8 = 8u;
        ccnt[(size_t)R*8 + bn] = c8;
        for (unsigned slot = 0; slot < c8; ++slot)
            ccode[((size_t)R*8 + bn)*8 + slot] = codesL[tid][slot];
    }
}

/* ---- rescore: wave per row; stage row to LDS, exact pairwise x2,
 * bit-exact numpy fp32 chain for all listed candidates (one per lane),
 * lexicographic (d, code) min == numpy first-min.                       ---- */
__global__ __launch_bounds__(256) void vq_rescore(const float* __restrict__ lat,
                                                  const float* __restrict__ cb,
                                                  const float* __restrict__ w2f,
                                                  const unsigned* __restrict__ ccnt,
                                                  const unsigned short* __restrict__ ccode,
                                                  int* __restrict__ idx,
                                                  double* __restrict__ loss_acc) {
    __shared__ float  xrow[4][256];
    __shared__ double part[4];
    const int tid = threadIdx.x;
    const int wv = tid >> 6, l = tid & 63;
    const int row = blockIdx.x * 4 + wv;
    const int b = row >> 10, t = row & 1023;

    /* stage latent row (scattered dwords; lines shared by 16 consecutive rows) */
    const float* base = lat + (size_t)b * Dd * Tt + t;
    float4 xv;
    xv.x = base[(size_t)(l*4+0) * Tt];
    xv.y = base[(size_t)(l*4+1) * Tt];
    xv.z = base[(size_t)(l*4+2) * Tt];
    xv.w = base[(size_t)(l*4+3) * Tt];
    *(float4*)&xrow[wv][l*4] = xv;
    __syncthreads();

    /* x2: exact numpy pairwise (two 128-halves, 8 accumulators, tree) */
    float s = 0.0f;
    if (l < 16) {
#pragma clang fp contract(off)
        const int h = l >> 3, j = l & 7;
        float v = xrow[wv][h*128 + j];
        float r8 = v * v;
        for (int m = 1; m < 16; ++m) {
            v = xrow[wv][h*128 + m*8 + j];
            r8 += v * v;
        }
        s = r8;
    }
    s += __shfl_xor(s, 1, 64);          /* (r0+r1).. pairs   */
    s += __shfl_xor(s, 2, 64);          /* ((..)+(..))       */
    s += __shfl_xor(s, 4, 64);          /* half sum h        */
    s += __shfl_xor(s, 8, 64);          /* h0 + h1 (commutative == numpy order) */
    const float x2r = __shfl(s, 0, 64);

    /* candidates: lane = slab*8 + slot */
    const int s8 = l >> 3, slot = l & 7;
    const unsigned cnt = ccnt[(size_t)row*8 + s8];
    int c = -1;
    if ((unsigned)slot < cnt) c = ccode[((size_t)row*8 + s8)*8 + slot];

    float dv = 3.4e38f; int cc = 1 << 20;
    if (c >= 0) {
        const float4* wq = (const float4*)(cb + (size_t)c * Dd);
        const float4* xq = (const float4*)&xrow[wv][0];
        float acc = 0.0f;
        for (int m = 0; m < 64; ++m) {              /* strict k-ascending fp32 chain */
            float4 xa = xq[m], wa = wq[m];
            acc = __builtin_fmaf(xa.x, wa.x, acc);
            acc = __builtin_fmaf(xa.y, wa.y, acc);
            acc = __builtin_fmaf(xa.z, wa.z, acc);
            acc = __builtin_fmaf(xa.w, wa.w, acc);
        }
        float t2 = x2r - 2.0f * acc;                /* fl(x2 - fl(2M)), 2*acc exact */
        dv = t2 + w2f[c];                           /* fl(.. + w2)                  */
        cc = c;
    }
    for (int off = 32; off; off >>= 1) {            /* lexicographic (dv, cc) min */
        float d2 = __shfl_xor(dv, off, 64);
        int   c2 = __shfl_xor(cc, off, 64);
        if (d2 < dv || (d2 == dv && c2 < cc)) { dv = d2; cc = c2; }
    }
    if (l == 0) { idx[row] = cc; part[wv] = (double)dv; }
    __syncthreads();
    if (tid == 0) atomicAdd(loss_acc, part[0] + part[1] + part[2] + part[3]);
}

/* ---- R5 fallback main (s_load path), used only if ws too small ---- */
typedef float float8_t __attribute__((ext_vector_type(8)));
__global__ __launch_bounds__(512) void vq_main(const float* __restrict__ latents,
                                               const float* __restrict__ cb,
                                               const float* __restrict__ w2f,
                                               int* __restrict__ idx,
                                               double* __restrict__ loss_acc) {
    __shared__ float  xs[Dd*64];
    __shared__ float  x2f[64];
    __shared__ float  bsd[8*64];
    __shared__ int    bci[8*64];
    __shared__ double red[64];
    const int tid = threadIdx.x;
    const int rr  = tid & 63;
    const int dg  = tid >> 6;
    const int blk = blockIdx.x;
    const int bb  = blk >> 4;
    const int t0  = (blk & 15) << 6;
    const float* lat = latents + (size_t)bb * Dd * Tt + t0;
    for (int d = dg; d < Dd; d += 8) xs[d*64 + rr] = lat[(size_t)d * Tt + rr];
    __syncthreads();
    if (tid < 64) {
#pragma clang fp contract(off)
        float h[2];
        for (int half = 0; half < 2; ++half) {
            float r[8];
            for (int j = 0; j < 8; ++j) { float v = xs[(half*128 + j)*64 + tid]; r[j] = v*v; }
            for (int m = 1; m < 16; ++m)
                for (int j = 0; j < 8; ++j) { float v = xs[(half*128 + m*8 + j)*64 + tid]; r[j] += v*v; }
            h[half] = ((r[0]+r[1]) + (r[2]+r[3])) + ((r[4]+r[5]) + (r[6]+r[7]));
        }
        x2f[tid] = h[0] + h[1];
    }
    __syncthreads();
    const int slab = __builtin_amdgcn_readfirstlane(tid >> 6);
    const int lane = tid & 63;
    const float x2r = x2f[lane];
    const float* wq = cb + (size_t)slab * 128 * Dd;
    float best = 3.4e38f; int bestc = 0;
    for (int cg = 0; cg < 16; ++cg) {
        const int c0 = cg * 8;
        float acc[8];
#pragma unroll
        for (int g = 0; g < 8; ++g) acc[g] = 0.0f;
        for (int kc = 0; kc < 32; ++kc) {
            float8_t w8[8];
#pragma unroll
            for (int g = 0; g < 8; ++g) w8[g] = *(const float8_t*)(wq + (size_t)(c0+g)*Dd + kc*8);
            float xk[8];
#pragma unroll
            for (int j = 0; j < 8; ++j) xk[j] = xs[(kc*8 + j)*64 + lane];
#pragma unroll
            for (int g = 0; g < 8; ++g)
#pragma unroll
                for (int j = 0; j < 8; ++j) acc[g] = __builtin_fmaf(xk[j], w8[g][j], acc[g]);
        }
#pragma unroll
        for (int g = 0; g < 8; ++g) {
            float t2 = x2r - 2.0f * acc[g];
            float dvv = t2 + w2f[slab*128 + c0 + g];
            if (dvv < best) { best = dvv; bestc = slab*128 + c0 + g; }
        }
    }
    bsd[slab*64 + lane] = best; bci[slab*64 + lane] = bestc;
    __syncthreads();
    if (tid < 64) {
        float b0 = bsd[tid]; int ci = bci[tid];
#pragma unroll
        for (int s = 1; s < 8; ++s) { float b1 = bsd[s*64 + tid]; if (b1 < b0) { b0 = b1; ci = bci[s*64 + tid]; } }
        idx[blk*64 + tid] = ci; red[tid] = (double)b0;
    }
    __syncthreads();
    if (tid == 0) { double s = 0.0; for (int i = 0; i < 64; ++i) s += red[i]; atomicAdd(loss_acc, s); }
}

/* ---- gather: out[b][d][t] = cb[idx[b*T+t]][d] ---- */
__global__ void vq_gather(const float* __restrict__ cb,
                          const int* __restrict__ idx,
                          float* __restrict__ out) {
    const size_t g = (size_t)blockIdx.x * 256 + threadIdx.x;
    const int t  = (int)(g & 1023);
    const int d4 = (int)((g >> 10) & 63);
    const int b  = (int)(g >> 16);
    const int i  = idx[b*Tt + t];
    const float4 w4 = *(const float4*)(cb + (size_t)i*Dd + d4*4);
    float* o = out + ((size_t)(b*Dd + d4*4)) * Tt + t;
    o[0]    = w4.x;
    o[Tt]   = w4.y;
    o[2*Tt] = w4.z;
    o[3*Tt] = w4.w;
}

/* ---- finalize: indices as float + loss ---- */
__global__ void vq_finalize(const int* __restrict__ idx,
                            const double* __restrict__ loss_acc,
                            float* __restrict__ out) {
    const int r = blockIdx.x * 256 + threadIdx.x;
    if (r < NROWS) out[OUTQ + 1 + r] = (float)idx[r];
    if (r == 0)    out[OUTQ] = (float)(1.25 * loss_acc[0] / (double)OUTQ);
}

extern "C" void kernel_launch(void* const* d_in, const int* in_sizes, int n_in,
                              void* d_out, int out_size, void* d_ws, size_t ws_size,
                              hipStream_t stream) {
    const float* latents = (const float*)d_in[0];
    const float* cb      = (const float*)d_in[1];
    float* out = (float*)d_out;
    char*  ws  = (char*)d_ws;

    double* loss = (double*)(ws + OFF_LOSS);
    float*  w2f  = (float*)(ws + OFF_W2);
    int*    idx  = (int*)(ws + OFF_IDX);

    hipMemsetAsync(loss, 0, sizeof(double), stream);
    vq_w2<<<4, 256, 0, stream>>>(cb, w2f);

    if (ws_size >= (size_t)MIN_WS) {
        unsigned*       ccnt  = (unsigned*)(ws + OFF_CCNT);
        unsigned short* ccode = (unsigned short*)(ws + OFF_CCODE);
        __bf16*         BT    = (__bf16*)(ws + OFF_BT);
        __bf16*         A     = (__bf16*)(ws + OFF_DYN);

        size_t avail = ws_size - OFF_DYN;
        long long rc = (long long)(avail / 1536);
        if (rc > NROWS) rc = NROWS;
        rc &= ~127LL;                                    /* multiple of 128 */

        vq_prep_bt<<<Kk, 256, 0, stream>>>(cb, BT);
        for (int r0 = 0; r0 < NROWS; r0 += (int)rc) {
            int MR = NROWS - r0; if (MR > rc) MR = (int)rc;
            vq_prep_a<<<dim3(MR/64, 4), 256, 0, stream>>>(latents, A, r0);
            vq_gemm<<<dim3(MR/128, 8), 256, 0, stream>>>(A, BT, w2f, ccnt, ccode, r0);
        }
        vq_rescore<<<NROWS/4, 256, 0, stream>>>(latents, cb, w2f, ccnt, ccode, idx, loss);
    } else {
        vq_main<<<NROWS/64, 512, 0, stream>>>(latents, cb, w2f, idx, loss);
    }

    vq_gather<<<(Bb*(Dd/4)*Tt)/256, 256, 0, stream>>>(cb, idx, out);
    vq_finalize<<<(NROWS + 255)/256, 256, 0, stream>>>(idx, loss, out);
}

// Round 8
// 303.473 us; speedup vs baseline: 3.4200x; 1.0724x over previous
//
#include <hip/hip_runtime.h>
#include <math.h>

#define Dd 256
#define Tt 1024
#define Bb 32
#define Kk 1024
#define NROWS (Bb*Tt)            /* 32768 */
#define OUTQ  (Bb*Dd*Tt)         /* 8388608 */
#define KP   512                 /* packed K: [hi | lo] . [hi | hi] */
#define SLACK 4e-4f

typedef __bf16 b16x8 __attribute__((ext_vector_type(8)));
typedef float  f32x4 __attribute__((ext_vector_type(4)));

/* workspace layout (bytes) */
#define OFF_LOSS  0                      /* double                 */
#define OFF_W2    256                    /* float[1024]            */
#define OFF_IDX   8192                   /* int[32768]             */
#define OFF_CCNT  139264                 /* u32[32768*8]   1 MB    */
#define OFF_CCODE 1187840                /* u16[32768*8*8] 4 MB    */
#define OFF_BT    5382144                /* bf16[1024*512] 1 MB    */
#define OFF_X     6430720                /* float[32768*256] 32 MB */
#define OFF_A     39985152               /* bf16[32768*512] 32 MB  */
#define MIN_WS    (OFF_A + (size_t)NROWS*KP*2)

/* ---- w2[k]: numpy-pairwise fp32 sum of w*w per codebook row ---- */
__global__ void vq_w2(const float* __restrict__ cb, float* __restrict__ w2f) {
#pragma clang fp contract(off)
    const int k = blockIdx.x * 256 + threadIdx.x;
    if (k >= Kk) return;
    const float* w = cb + (size_t)k * Dd;
    float h[2];
    for (int half = 0; half < 2; ++half) {
        const float* p = w + half * 128;
        float r[8];
        for (int j = 0; j < 8; ++j) { float v = p[j]; r[j] = v * v; }
        for (int m = 1; m < 16; ++m)
            for (int j = 0; j < 8; ++j) { float v = p[m*8 + j]; r[j] += v * v; }
        h[half] = ((r[0]+r[1]) + (r[2]+r[3])) + ((r[4]+r[5]) + (r[6]+r[7]));
    }
    w2f[k] = h[0] + h[1];
}

/* ---- BT[c][k]: packed [w_hi | w_hi], bf16 ---- */
__global__ void vq_prep_bt(const float* __restrict__ cb, __bf16* __restrict__ BT) {
    const int c = blockIdx.x, t = threadIdx.x;          /* 1024 x 256 */
    float v = cb[(size_t)c*Dd + t];
    __bf16 hi = (__bf16)v;
    BT[(size_t)c*KP + t]       = hi;
    BT[(size_t)c*KP + 256 + t] = hi;
}

/* ---- transpose latents -> X[r][d] fp32 + A[r][k] packed [x_hi | x_lo] ---- */
__global__ void vq_prep_a(const float* __restrict__ lat, float* __restrict__ X,
                          __bf16* __restrict__ A) {
    __shared__ float tl[64][65];
    const int tid = threadIdx.x;
    const int rowbase = blockIdx.x * 64;                /* global row, mult of 64 */
    const int b = rowbase >> 10, t0 = rowbase & 1023;
    const int d0 = blockIdx.y * 64;
    const int tt = tid & 63, sub = tid >> 6;
#pragma unroll
    for (int it = 0; it < 16; ++it) {
        int d = it*4 + sub;
        tl[d][tt] = lat[((size_t)(b*Dd + d0 + d))*Tt + t0 + tt];
    }
    __syncthreads();
    const int dd = tid & 63;
#pragma unroll
    for (int it = 0; it < 16; ++it) {
        int t = it*4 + sub;
        float v = tl[dd][t];
        int grow = rowbase + t;
        X[(size_t)grow*Dd + d0 + dd] = v;
        __bf16 hi = (__bf16)v;
        __bf16 lo = (__bf16)(v - (float)hi);
        size_t ab = (size_t)grow*KP + d0 + dd;
        A[ab]       = hi;
        A[ab + 256] = lo;
    }
}

/* ---- filter GEMM + fused min/candidate epilogue ----
 * 128x128 C-tile (bm=row-block, bn=code-slab), 4 waves 2x2, 4x4 frags of
 * 16x16x32 bf16 MFMA, K=512. f = w2 - 2S, S = x.w_hi exactly (2-term).
 * Epilogue: per-row slab-min + candidates f <= slabmin + SLACK (cap 8). */
__global__ __launch_bounds__(256) void vq_gemm(const __bf16* __restrict__ A,
                                               const __bf16* __restrict__ BT,
                                               const float* __restrict__ w2f,
                                               unsigned* __restrict__ ccnt,
                                               unsigned short* __restrict__ ccode) {
    __shared__ __bf16 As[128][72];
    __shared__ __bf16 Bs[128][72];
    __shared__ float  rminS[128][2];
    __shared__ unsigned cntL[128];
    __shared__ unsigned short codesL[128][8];

    const int tid = threadIdx.x;
    const int bm = blockIdx.x, bn = blockIdx.y;
    const int l = tid & 63, wv = tid >> 6;
    const int wm = (wv & 1) * 64, wn = (wv >> 1) * 64;
    const int m16 = l & 15, quad = l >> 4;

    if (tid < 128) cntL[tid] = 0u;

    f32x4 acc[4][4];
#pragma unroll
    for (int i = 0; i < 4; ++i)
#pragma unroll
        for (int j = 0; j < 4; ++j) acc[i][j] = (f32x4){0.f,0.f,0.f,0.f};

    const int sr = tid >> 3;            /* 0..31 */
    const int sk = (tid & 7) * 8;       /* 0..56 */

    for (int kt = 0; kt < 8; ++kt) {    /* K=512: 8 tiles of 64 */
        const int k0 = kt * 64;
#pragma unroll
        for (int p = 0; p < 4; ++p) {
            int r = sr + p*32;
            *(uint4*)&As[r][sk] = *(const uint4*)&A [(size_t)(bm*128 + r)*KP + k0 + sk];
            *(uint4*)&Bs[r][sk] = *(const uint4*)&BT[(size_t)(bn*128 + r)*KP + k0 + sk];
        }
        __syncthreads();
#pragma unroll
        for (int ks = 0; ks < 64; ks += 32) {
            b16x8 a[4], b[4];
#pragma unroll
            for (int i = 0; i < 4; ++i) a[i] = *(const b16x8*)&As[wm + 16*i + m16][ks + quad*8];
#pragma unroll
            for (int j = 0; j < 4; ++j) b[j] = *(const b16x8*)&Bs[wn + 16*j + m16][ks + quad*8];
#pragma unroll
            for (int i = 0; i < 4; ++i)
#pragma unroll
                for (int j = 0; j < 4; ++j)
                    acc[i][j] = __builtin_amdgcn_mfma_f32_16x16x32_bf16(a[i], b[j], acc[i][j], 0, 0, 0);
        }
        __syncthreads();
    }

    /* ---- epilogue: per-row slab-min + candidates ---- */
    float w2n[4];
#pragma unroll
    for (int j = 0; j < 4; ++j) w2n[j] = w2f[bn*128 + wn + 16*j + m16];

    float vmin[4][4];
#pragma unroll
    for (int i = 0; i < 4; ++i)
#pragma unroll
        for (int g = 0; g < 4; ++g) {
            float v = w2n[0] - 2.0f * acc[i][0][g];
#pragma unroll
            for (int j = 1; j < 4; ++j)
                v = fminf(v, w2n[j] - 2.0f * acc[i][j][g]);
#pragma unroll
            for (int off = 1; off <= 8; off <<= 1)
                v = fminf(v, __shfl_xor(v, off, 64));   /* min over m16 group */
            vmin[i][g] = v;
        }
    if (m16 == 0) {
#pragma unroll
        for (int i = 0; i < 4; ++i)
#pragma unroll
            for (int g = 0; g < 4; ++g)
                rminS[wm + 16*i + quad*4 + g][wn >> 6] = vmin[i][g];
    }
    __syncthreads();
#pragma unroll
    for (int i = 0; i < 4; ++i)
#pragma unroll
        for (int g = 0; g < 4; ++g) {
            const int rloc = wm + 16*i + quad*4 + g;
            const float thr = fminf(rminS[rloc][0], rminS[rloc][1]) + SLACK;
#pragma unroll
            for (int j = 0; j < 4; ++j) {
                float f = w2n[j] - 2.0f * acc[i][j][g];
                if (f <= thr) {
                    unsigned slot = atomicAdd(&cntL[rloc], 1u);
                    if (slot < 8u)
                        codesL[rloc][slot] = (unsigned short)(bn*128 + wn + 16*j + m16);
                }
            }
        }
    __syncthreads();
    if (tid < 128) {
        const int R = bm*128 + tid;
        unsigned c8 = cntL[tid]; if (c8 > 8u) c8 = 8u;
        ccnt[(size_t)R*8 + bn] = c8;
        for (unsigned slot = 0; slot < c8; ++slot)
            ccode[((size_t)R*8 + bn)*8 + slot] = codesL[tid][slot];
    }
}

/* ---- rescore: wave per row; coalesced X-row stage to LDS, exact pairwise
 * x2, bit-exact numpy fp32 chain for all candidates (one per lane),
 * lexicographic (d, code) min == numpy first-min.                       ---- */
__global__ __launch_bounds__(256) void vq_rescore(const float* __restrict__ X,
                                                  const float* __restrict__ cb,
                                                  const float* __restrict__ w2f,
                                                  const unsigned* __restrict__ ccnt,
                                                  const unsigned short* __restrict__ ccode,
                                                  int* __restrict__ idx,
                                                  double* __restrict__ loss_acc) {
    __shared__ float  xrow[4][256];
    __shared__ double part[4];
    const int tid = threadIdx.x;
    const int wv = tid >> 6, l = tid & 63;
    const int row = blockIdx.x * 4 + wv;

    /* stage X row: one coalesced float4 per lane */
    const float4* xg = (const float4*)(X + (size_t)row * Dd);
    *(float4*)&xrow[wv][l*4] = xg[l];
    __syncthreads();

    /* x2: exact numpy pairwise (two 128-halves, 8 accumulators, tree) */
    float s = 0.0f;
    if (l < 16) {
#pragma clang fp contract(off)
        const int h = l >> 3, j = l & 7;
        float v = xrow[wv][h*128 + j];
        float r8 = v * v;
        for (int m = 1; m < 16; ++m) {
            v = xrow[wv][h*128 + m*8 + j];
            r8 += v * v;
        }
        s = r8;
    }
    s += __shfl_xor(s, 1, 64);
    s += __shfl_xor(s, 2, 64);
    s += __shfl_xor(s, 4, 64);
    s += __shfl_xor(s, 8, 64);          /* == numpy pairwise combine (commutative) */
    const float x2r = __shfl(s, 0, 64);

    /* candidates: lane = slab*8 + slot */
    const int s8 = l >> 3, slot = l & 7;
    const unsigned cnt = ccnt[(size_t)row*8 + s8];
    int c = -1;
    if ((unsigned)slot < cnt) c = ccode[((size_t)row*8 + s8)*8 + slot];

    float dv = 3.4e38f; int cc = 1 << 20;
    if (c >= 0) {
        const float4* wq = (const float4*)(cb + (size_t)c * Dd);
        const float4* xq = (const float4*)&xrow[wv][0];
        float acc = 0.0f;
        for (int m = 0; m < 64; ++m) {              /* strict k-ascending fp32 chain */
            float4 xa = xq[m], wa = wq[m];
            acc = __builtin_fmaf(xa.x, wa.x, acc);
            acc = __builtin_fmaf(xa.y, wa.y, acc);
            acc = __builtin_fmaf(xa.z, wa.z, acc);
            acc = __builtin_fmaf(xa.w, wa.w, acc);
        }
        float t2 = x2r - 2.0f * acc;                /* fl(x2 - fl(2M)), 2*acc exact */
        dv = t2 + w2f[c];                           /* fl(.. + w2)                  */
        cc = c;
    }
    for (int off = 32; off; off >>= 1) {            /* lexicographic (dv, cc) min */
        float d2 = __shfl_xor(dv, off, 64);
        int   c2 = __shfl_xor(cc, off, 64);
        if (d2 < dv || (d2 == dv && c2 < cc)) { dv = d2; cc = c2; }
    }
    if (l == 0) { idx[row] = cc; part[wv] = (double)dv; }
    __syncthreads();
    if (tid == 0) atomicAdd(loss_acc, part[0] + part[1] + part[2] + part[3]);
}

/* ---- R5 fallback main (s_load path), used only if ws too small ---- */
typedef float float8_t __attribute__((ext_vector_type(8)));
__global__ __launch_bounds__(512) void vq_main(const float* __restrict__ latents,
                                               const float* __restrict__ cb,
                                               const float* __restrict__ w2f,
                                               int* __restrict__ idx,
                                               double* __restrict__ loss_acc) {
    __shared__ float  xs[Dd*64];
    __shared__ float  x2f[64];
    __shared__ float  bsd[8*64];
    __shared__ int    bci[8*64];
    __shared__ double red[64];
    const int tid = threadIdx.x;
    const int rr  = tid & 63;
    const int dg  = tid >> 6;
    const int blk = blockIdx.x;
    const int bb  = blk >> 4;
    const int t0  = (blk & 15) << 6;
    const float* lat = latents + (size_t)bb * Dd * Tt + t0;
    for (int d = dg; d < Dd; d += 8) xs[d*64 + rr] = lat[(size_t)d * Tt + rr];
    __syncthreads();
    if (tid < 64) {
#pragma clang fp contract(off)
        float h[2];
        for (int half = 0; half < 2; ++half) {
            float r[8];
            for (int j = 0; j < 8; ++j) { float v = xs[(half*128 + j)*64 + tid]; r[j] = v*v; }
            for (int m = 1; m < 16; ++m)
                for (int j = 0; j < 8; ++j) { float v = xs[(half*128 + m*8 + j)*64 + tid]; r[j] += v*v; }
            h[half] = ((r[0]+r[1]) + (r[2]+r[3])) + ((r[4]+r[5]) + (r[6]+r[7]));
        }
        x2f[tid] = h[0] + h[1];
    }
    __syncthreads();
    const int slab = __builtin_amdgcn_readfirstlane(tid >> 6);
    const int lane = tid & 63;
    const float x2r = x2f[lane];
    const float* wq = cb + (size_t)slab * 128 * Dd;
    float best = 3.4e38f; int bestc = 0;
    for (int cg = 0; cg < 16; ++cg) {
        const int c0 = cg * 8;
        float acc[8];
#pragma unroll
        for (int g = 0; g < 8; ++g) acc[g] = 0.0f;
        for (int kc = 0; kc < 32; ++kc) {
            float8_t w8[8];
#pragma unroll
            for (int g = 0; g < 8; ++g) w8[g] = *(const float8_t*)(wq + (size_t)(c0+g)*Dd + kc*8);
            float xk[8];
#pragma unroll
            for (int j = 0; j < 8; ++j) xk[j] = xs[(kc*8 + j)*64 + lane];
#pragma unroll
            for (int g = 0; g < 8; ++g)
#pragma unroll
                for (int j = 0; j < 8; ++j) acc[g] = __builtin_fmaf(xk[j], w8[g][j], acc[g]);
        }
#pragma unroll
        for (int g = 0; g < 8; ++g) {
            float t2 = x2r - 2.0f * acc[g];
            float dvv = t2 + w2f[slab*128 + c0 + g];
            if (dvv < best) { best = dvv; bestc = slab*128 + c0 + g; }
        }
    }
    bsd[slab*64 + lane] = best; bci[slab*64 + lane] = bestc;
    __syncthreads();
    if (tid < 64) {
        float b0 = bsd[tid]; int ci = bci[tid];
#pragma unroll
        for (int s = 1; s < 8; ++s) { float b1 = bsd[s*64 + tid]; if (b1 < b0) { b0 = b1; ci = bci[s*64 + tid]; } }
        idx[blk*64 + tid] = ci; red[tid] = (double)b0;
    }
    __syncthreads();
    if (tid == 0) { double s = 0.0; for (int i = 0; i < 64; ++i) s += red[i]; atomicAdd(loss_acc, s); }
}

/* ---- gather: out[b][d][t] = cb[idx[b*T+t]][d] ---- */
__global__ void vq_gather(const float* __restrict__ cb,
                          const int* __restrict__ idx,
                          float* __restrict__ out) {
    const size_t g = (size_t)blockIdx.x * 256 + threadIdx.x;
    const int t  = (int)(g & 1023);
    const int d4 = (int)((g >> 10) & 63);
    const int b  = (int)(g >> 16);
    const int i  = idx[b*Tt + t];
    const float4 w4 = *(const float4*)(cb + (size_t)i*Dd + d4*4);
    float* o = out + ((size_t)(b*Dd + d4*4)) * Tt + t;
    o[0]    = w4.x;
    o[Tt]   = w4.y;
    o[2*Tt] = w4.z;
    o[3*Tt] = w4.w;
}

/* ---- finalize: indices as float + loss ---- */
__global__ void vq_finalize(const int* __restrict__ idx,
                            const double* __restrict__ loss_acc,
                            float* __restrict__ out) {
    const int r = blockIdx.x * 256 + threadIdx.x;
    if (r < NROWS) out[OUTQ + 1 + r] = (float)idx[r];
    if (r == 0)    out[OUTQ] = (float)(1.25 * loss_acc[0] / (double)OUTQ);
}

extern "C" void kernel_launch(void* const* d_in, const int* in_sizes, int n_in,
                              void* d_out, int out_size, void* d_ws, size_t ws_size,
                              hipStream_t stream) {
    const float* latents = (const float*)d_in[0];
    const float* cb      = (const float*)d_in[1];
    float* out = (float*)d_out;
    char*  ws  = (char*)d_ws;

    double* loss = (double*)(ws + OFF_LOSS);
    float*  w2f  = (float*)(ws + OFF_W2);
    int*    idx  = (int*)(ws + OFF_IDX);

    hipMemsetAsync(loss, 0, sizeof(double), stream);
    vq_w2<<<4, 256, 0, stream>>>(cb, w2f);

    if (ws_size >= (size_t)MIN_WS) {
        unsigned*       ccnt  = (unsigned*)(ws + OFF_CCNT);
        unsigned short* ccode = (unsigned short*)(ws + OFF_CCODE);
        __bf16*         BT    = (__bf16*)(ws + OFF_BT);
        float*          X     = (float*)(ws + OFF_X);
        __bf16*         A     = (__bf16*)(ws + OFF_A);

        vq_prep_bt<<<Kk, 256, 0, stream>>>(cb, BT);
        vq_prep_a<<<dim3(NROWS/64, 4), 256, 0, stream>>>(latents, X, A);
        vq_gemm<<<dim3(NROWS/128, 8), 256, 0, stream>>>(A, BT, w2f, ccnt, ccode);
        vq_rescore<<<NROWS/4, 256, 0, stream>>>(X, cb, w2f, ccnt, ccode, idx, loss);
    } else {
        vq_main<<<NROWS/64, 512, 0, stream>>>(latents, cb, w2f, idx, loss);
    }

    vq_gather<<<(Bb*(Dd/4)*Tt)/256, 256, 0, stream>>>(cb, idx, out);
    vq_finalize<<<(NROWS + 255)/256, 256, 0, stream>>>(idx, loss, out);
}